// Round 1
// baseline (34.670 us; speedup 1.0000x reference)
//
#include <hip/hip_runtime.h>
#include <math.h>

// Problem constants (from reference): B=16, T=2048, N=1024
#define TTOT   32768          // B*T
#define NNEUR  1024
#define NCHUNK 256            // outer time chunks (128 steps each)
#define SUBLEN 32             // time steps per thread (4 sub-chunks per block)

struct SegState { float cnt, first, last, g2; };

__device__ inline SegState seg_combine(SegState a, SegState b) {
    if (a.cnt == 0.0f) return b;
    if (b.cnt == 0.0f) return a;
    SegState r;
    float gap = b.first - a.last;   // crossing ISI
    r.cnt   = a.cnt + b.cnt;
    r.first = a.first;
    r.last  = b.last;
    r.g2    = a.g2 + b.g2 + gap * gap;
    return r;
}

// Kernel 1: streaming segmented scan.
// grid = (NNEUR/256, NCHUNK), block = 256 threads.
// Thread layout: ccol = tid&63 selects a float4 column (4 neurons),
//                ysl  = tid>>6 selects one of 4 sub-chunks of 32 steps.
__global__ __launch_bounds__(256) void k_scan(const float* __restrict__ s,
                                              float4* __restrict__ wstate) {
    const int tid  = threadIdx.x;
    const int ccol = tid & 63;
    const int ysl  = tid >> 6;
    const int col4 = blockIdx.x * 64 + ccol;       // float4 column index, 0..255
    const int t0   = blockIdx.y * 128 + ysl * 32;  // first time step for this thread

    const float4* s4 = reinterpret_cast<const float4*>(s);

    float cnt[4]  = {0.f, 0.f, 0.f, 0.f};
    float first[4] = {-1.f, -1.f, -1.f, -1.f};
    float last[4]  = {-1.f, -1.f, -1.f, -1.f};
    float g2[4]   = {0.f, 0.f, 0.f, 0.f};

    #pragma unroll 4
    for (int i = 0; i < SUBLEN; ++i) {
        const int t = t0 + i;
        const float4 v = s4[(size_t)t * 256 + col4];
        const float tt = (float)t;
        float vals[4] = {v.x, v.y, v.z, v.w};
        #pragma unroll
        for (int j = 0; j < 4; ++j) {
            if (vals[j] > 0.0f) {
                if (cnt[j] > 0.0f) {
                    float g = tt - last[j];
                    g2[j] += g * g;
                } else {
                    first[j] = tt;
                }
                last[j] = tt;
                cnt[j] += 1.0f;
            }
        }
    }

    // Combine the 4 sub-chunks (time-ordered: ysl 0..3) per neuron in LDS.
    __shared__ float4 lds[4][64][4];   // [ysl][ccol][neuron-in-quad] = 16 KiB
    #pragma unroll
    for (int j = 0; j < 4; ++j)
        lds[ysl][ccol][j] = make_float4(cnt[j], first[j], last[j], g2[j]);
    __syncthreads();

    if (ysl == 0) {
        #pragma unroll
        for (int j = 0; j < 4; ++j) {
            float4 a = lds[0][ccol][j];
            SegState st = {a.x, a.y, a.z, a.w};
            #pragma unroll
            for (int y = 1; y < 4; ++y) {
                float4 b = lds[y][ccol][j];
                SegState sb = {b.x, b.y, b.z, b.w};
                st = seg_combine(st, sb);
            }
            int neuron = col4 * 4 + j;
            wstate[(size_t)blockIdx.y * NNEUR + neuron] =
                make_float4(st.cnt, st.first, st.last, st.g2);
        }
    }
}

// Kernel 2: per-neuron combine across NCHUNK chunk-states + finalize CV.
// One wave (64 lanes) per neuron; block = 256 threads = 4 neurons.
__global__ __launch_bounds__(256) void k_combine(const float4* __restrict__ wstate,
                                                 const float* __restrict__ target,
                                                 float* __restrict__ outsq,
                                                 float* __restrict__ outvalid) {
    const int tid  = threadIdx.x;
    const int lane = tid & 63;
    const int w    = tid >> 6;
    const int n    = blockIdx.x * 4 + w;

    SegState st = {0.f, -1.f, -1.f, 0.f};
    #pragma unroll
    for (int j = 0; j < 4; ++j) {
        int c = lane * 4 + j;          // chunks in ascending time order per lane
        float4 a = wstate[(size_t)c * NNEUR + n];
        SegState sb = {a.x, a.y, a.z, a.w};
        st = seg_combine(st, sb);
    }
    // Order-preserving binary tree reduction across 64 lanes.
    for (int off = 1; off < 64; off <<= 1) {
        SegState other;
        other.cnt   = __shfl_down(st.cnt,   off);
        other.first = __shfl_down(st.first, off);
        other.last  = __shfl_down(st.last,  off);
        other.g2    = __shfl_down(st.g2,    off);
        if ((lane & (2 * off - 1)) == 0)
            st = seg_combine(st, other);
    }

    if (lane == 0) {
        float k     = st.cnt;
        float n_isi = k - 1.0f;
        float sum_g = (k > 0.0f) ? (st.last - st.first) : 0.0f;  // telescoped gap sum
        float mean  = sum_g / fmaxf(n_isi, 1.0f);
        float var   = (st.g2 - n_isi * mean * mean) / fmaxf(n_isi - 1.0f, 1.0f);
        float sd    = sqrtf(fmaxf(var, 0.0f));
        bool valid  = (k >= 3.0f) && (mean > 0.0f);
        float cv    = valid ? sd / mean : 0.0f;
        float tc    = target[n];
        float d     = cv - tc;
        outsq[n]    = valid ? d * d : 0.0f;
        outvalid[n] = valid ? 1.0f : 0.0f;
    }
}

// Kernel 3: deterministic reduction of 1024 per-neuron values -> scalar loss.
__global__ __launch_bounds__(256) void k_reduce(const float* __restrict__ outsq,
                                                const float* __restrict__ outvalid,
                                                float* __restrict__ out) {
    const int tid = threadIdx.x;
    float s = 0.f, v = 0.f;
    for (int i = tid; i < NNEUR; i += 256) {
        s += outsq[i];
        v += outvalid[i];
    }
    for (int off = 32; off > 0; off >>= 1) {
        s += __shfl_down(s, off);
        v += __shfl_down(v, off);
    }
    __shared__ float ls[4], lv[4];
    const int w = tid >> 6;
    if ((tid & 63) == 0) { ls[w] = s; lv[w] = v; }
    __syncthreads();
    if (tid == 0) {
        float S = ls[0] + ls[1] + ls[2] + ls[3];
        float V = lv[0] + lv[1] + lv[2] + lv[3];
        out[0] = (V > 0.0f) ? S / fmaxf(V, 1.0f) : 0.0f;
    }
}

extern "C" void kernel_launch(void* const* d_in, const int* in_sizes, int n_in,
                              void* d_out, int out_size, void* d_ws, size_t ws_size,
                              hipStream_t stream) {
    const float* spikes = (const float*)d_in[0];   // (B*T*N) fp32
    const float* target = (const float*)d_in[1];   // (N,) fp32
    float* out = (float*)d_out;

    // Workspace layout:
    //  [0, 4MB)            : float4 wstate[NCHUNK * NNEUR]
    //  [4MB, +4KB)         : float outsq[NNEUR]
    //  [4MB+4KB, +4KB)     : float outvalid[NNEUR]
    char* wsb = (char*)d_ws;
    float4* wstate  = (float4*)wsb;
    float*  outsq   = (float*)(wsb + (size_t)NCHUNK * NNEUR * sizeof(float4));
    float*  outvalid = outsq + NNEUR;

    dim3 g1(NNEUR / 256, NCHUNK);
    k_scan<<<g1, 256, 0, stream>>>(spikes, wstate);
    k_combine<<<NNEUR / 4, 256, 0, stream>>>(wstate, target, outsq, outvalid);
    k_reduce<<<1, 256, 0, stream>>>(outsq, outvalid, out);
}